// Round 24
// baseline (33.072 us; speedup 1.0000x reference)
//
#include <hip/hip_runtime.h>

#define N_B 8
#define DIM 256

constexpr float C2    = 2.8853900817779268f;   // 2*log2(e)
constexpr float LOG2E = 1.4426950408889634f;

typedef __attribute__((ext_vector_type(8))) short short8;
typedef __attribute__((ext_vector_type(4))) float f32x4;
typedef unsigned short ushort_t;

__device__ __forceinline__ unsigned hi2(float a, float b) {
    return (__float_as_uint(a) >> 16) | (__float_as_uint(b) & 0xFFFF0000u);
}
__device__ __forceinline__ float trunc_res(float a) {
    return a - __uint_as_float(__float_as_uint(a) & 0xFFFF0000u);
}

// ---------------- proj (MFMA): 32x64 tiles, grid 512 (2 blocks/CU), A hi-only ----------------
__global__ __launch_bounds__(512, 2) void proj_mfma(
    const float* __restrict__ query, const float* __restrict__ key,
    const float* __restrict__ Wq, const float* __restrict__ Wk,
    float* __restrict__ EQ, float* __restrict__ EK)
{
    __shared__ __align__(16) ushort_t Ah[32 * 64], Bh[64 * 64], Bl[64 * 64];
    __shared__ __align__(16) float T[2304];

    int bid = blockIdx.x;
    int y = bid & 15;
    int x = bid >> 4;
    int b = y >> 1; bool isK = y & 1;
    const float* A    = (isK ? key : query) + b * DIM * DIM;
    const float* Wsrc = isK ? Wk : Wq;

    int R0 = (x >> 2) * 32, C0 = (x & 3) * 64;

    int tid = threadIdx.x;
    int w = tid >> 6, lane = tid & 63;
    int wr = w >> 2, wc = w & 3;
    int l15 = lane & 15, l4 = lane >> 4;

    int sr = tid >> 4, skq = (tid & 15) * 4;
    int kp = tid & 31, cg = tid >> 5;

    f32x4 acc = {};
    float4 areg;
    float4 w00, w10;

    {
        areg = *(const float4*)&A[(size_t)(R0 + sr) * DIM + skq];
        const float* wp0 = &Wsrc[(size_t)(2 * kp)     * DIM + C0 + cg * 4];
        const float* wp1 = &Wsrc[(size_t)(2 * kp + 1) * DIM + C0 + cg * 4];
        w00 = *(const float4*)&wp0[0];
        w10 = *(const float4*)&wp1[0];
    }

    for (int ks = 0; ks < 4; ++ks) {
        {
            int i0 = (sr * 64 + skq) ^ ((sr & 7) << 3);
            *(uint2*)&Ah[i0] = make_uint2(hi2(areg.x, areg.y), hi2(areg.z, areg.w));
            float a0[4] = {w00.x, w00.y, w00.z, w00.w};
            float a1[4] = {w10.x, w10.y, w10.z, w10.w};
#pragma unroll
            for (int c = 0; c < 4; ++c) {
                int col = cg * 4 + c;
                int idx = (col * 64 + 2 * kp) ^ ((col & 7) << 3);
                *(unsigned*)&Bh[idx] = hi2(a0[c], a1[c]);
                *(unsigned*)&Bl[idx] = hi2(trunc_res(a0[c]), trunc_res(a1[c]));
            }
        }
        __syncthreads();
        if (ks < 3) {
            int K0 = (ks + 1) * 64;
            areg = *(const float4*)&A[(size_t)(R0 + sr) * DIM + K0 + skq];
            const float* wp0 = &Wsrc[(size_t)(K0 + 2 * kp)     * DIM + C0 + cg * 4];
            const float* wp1 = &Wsrc[(size_t)(K0 + 2 * kp + 1) * DIM + C0 + cg * 4];
            w00 = *(const float4*)&wp0[0];
            w10 = *(const float4*)&wp1[0];
        }
#pragma unroll
        for (int kk = 0; kk < 2; ++kk) {
            int kb = kk * 32 + l4 * 8;
            short8 ah, bh, bl;
            {
                int arow = wr * 16 + l15;
                int aidx = (arow * 64 + kb) ^ ((arow & 7) << 3);
                ah = *(const short8*)&Ah[aidx];
            }
            {
                int bcol = wc * 16 + l15;
                int bidx = (bcol * 64 + kb) ^ ((bcol & 7) << 3);
                bh = *(const short8*)&Bh[bidx];
                bl = *(const short8*)&Bl[bidx];
            }
            acc = __builtin_amdgcn_mfma_f32_16x16x32_bf16(ah, bh, acc, 0, 0, 0);
            acc = __builtin_amdgcn_mfma_f32_16x16x32_bf16(ah, bl, acc, 0, 0, 0);
        }
        __syncthreads();
    }

    {
        float ev[4];
#pragma unroll
        for (int v = 0; v < 4; ++v) ev[v] = __builtin_amdgcn_exp2f(C2 * acc[v]);
        int row = wr * 16 + l4 * 4;
        int col = wc * 16 + l15;
        if (isK) {
#pragma unroll
            for (int v = 0; v < 4; ++v) T[(row + v) * 68 + col] = ev[v];
        } else {
            *(float4*)&T[col * 36 + row] = make_float4(ev[0], ev[1], ev[2], ev[3]);
        }
    }
    __syncthreads();
    if (isK) {
        int r = tid >> 4, q = tid & 15;
        float* dst = &EK[(size_t)b * DIM * DIM + (size_t)(R0 + r) * DIM + C0 + q * 4];
        *(float4*)dst = *(const float4*)&T[r * 68 + q * 4];
    } else {
        int r = tid >> 3, q = tid & 7;
        float* dst = &EQ[(size_t)b * DIM * DIM + (size_t)(C0 + r) * DIM + R0 + q * 4];
        *(float4*)dst = *(const float4*)&T[r * 36 + q * 4];
    }
}

// ---------------- fused scores + softmax(axis=n) -> attnN hi bf16 [n][m] ----------------
// 1D grid 512 (b = bid&7); MBLK=4, 512 thr = 8 waves = 4 hs x 2 mg.
// 4-way rcp combine: one rcp per 4 h-terms (14 VALU + 1 rcp vs 12 + 2).
#define SCORES_CHUNK(QC, CIDX)                                                          \
    {                                                                                   \
        float4 wv4 = *(const float4*)&Ws[(CIDX) * 16 + hs * 4];                         \
        float w0 = wv4.x, w1 = wv4.y, w2 = wv4.z, w3 = wv4.w;                           \
        float eka[2][4];                                                                \
        _Pragma("unroll")                                                               \
        for (int i = 0; i < 2; ++i) {                                                   \
            float4 e4 = *(const float4*)&Eks[mg * 2 + i][(CIDX) * 16 + hs * 4];         \
            eka[i][0] = e4.x; eka[i][1] = e4.y; eka[i][2] = e4.z; eka[i][3] = e4.w;     \
        }                                                                               \
        float qa[4][4];                                                                 \
        _Pragma("unroll")                                                               \
        for (int r = 0; r < 4; ++r) {                                                   \
            qa[r][0] = QC[r].x; qa[r][1] = QC[r].y;                                     \
            qa[r][2] = QC[r].z; qa[r][3] = QC[r].w;                                     \
        }                                                                               \
        __builtin_amdgcn_s_setprio(1);                                                  \
        _Pragma("unroll")                                                               \
        for (int i = 0; i < 2; ++i) {                                                   \
            float e0 = eka[i][0], e1 = eka[i][1], e2 = eka[i][2], e3 = eka[i][3];       \
            _Pragma("unroll")                                                           \
            for (int j = 0; j < 4; ++j) {                                               \
                float d0 = fmaf(qa[0][j], e0, 1.0f);                                    \
                float d1 = fmaf(qa[1][j], e1, 1.0f);                                    \
                float d2 = fmaf(qa[2][j], e2, 1.0f);                                    \
                float d3 = fmaf(qa[3][j], e3, 1.0f);                                    \
                float p01 = d0 * d1, p23 = d2 * d3;                                     \
                float n01 = fmaf(w0, d1, w1 * d0);                                      \
                float n23 = fmaf(w2, d3, w3 * d2);                                      \
                float num = fmaf(n01, p23, n23 * p01);                                  \
                acc[i][j] = fmaf(num, __builtin_amdgcn_rcpf(p01 * p23), acc[i][j]);     \
            }                                                                           \
        }                                                                               \
        __builtin_amdgcn_s_setprio(0);                                                  \
    }

__global__ __launch_bounds__(512, 2) void scores_softmax_kernel(
    const float* __restrict__ EQ, const float* __restrict__ EK,
    const float* __restrict__ Wv, ushort_t* __restrict__ ANh)
{
    int bid = blockIdx.x;
    int b  = bid & 7;
    int M0 = (bid >> 3) * 4;
    const float* Qb = EQ + b * DIM * DIM;   // [h][n]
    const float* Kb = EK + b * DIM * DIM;   // [m][h]

    __shared__ __align__(16) float Eks[4][DIM];
    __shared__ __align__(16) float Ws[DIM];
    __shared__ __align__(16) float part[3][2][64][8];

    int tid  = threadIdx.x;
    int w = tid >> 6, lane = tid & 63;
    int hs = w & 3, mg = w >> 2;
    int n0 = lane * 4;

    {
        int row = tid >> 7, h2 = (tid & 127) * 2;
        *(float2*)&Eks[row][h2] = *(const float2*)&Kb[(M0 + row) * DIM + h2];
    }
    if (tid < 64) *(float4*)&Ws[tid * 4] = *(const float4*)&Wv[tid * 4];

    float wsum = Wv[lane] + Wv[lane + 64] + Wv[lane + 128] + Wv[lane + 192];
#pragma unroll
    for (int o = 32; o; o >>= 1) wsum += __shfl_xor(wsum, o);
    __syncthreads();

    float acc[2][4] = {};
    const float* qbase = Qb + (hs * 4) * 256 + n0;

    float4 qA[4], qB[4];
#pragma unroll
    for (int r = 0; r < 4; ++r) qA[r] = *(const float4*)&qbase[r * 256];

    for (int c = 0; c < 16; c += 2) {
        {
            const float* qc = qbase + (c + 1) * 4096;
#pragma unroll
            for (int r = 0; r < 4; ++r) qB[r] = *(const float4*)&qc[r * 256];
        }
        SCORES_CHUNK(qA, c)
        if (c + 2 < 16) {
            const float* qc = qbase + (c + 2) * 4096;
#pragma unroll
            for (int r = 0; r < 4; ++r) qA[r] = *(const float4*)&qc[r * 256];
        }
        SCORES_CHUNK(qB, (c + 1))
    }

    if (hs) {
#pragma unroll
        for (int i = 0; i < 2; ++i) {
            float4 v = make_float4(acc[i][0], acc[i][1], acc[i][2], acc[i][3]);
            *(float4*)&part[hs - 1][mg][lane][i * 4] = v;
        }
    }
    __syncthreads();
    if (hs == 0) {
#pragma unroll
        for (int p = 0; p < 3; ++p)
#pragma unroll
            for (int i = 0; i < 2; ++i) {
                float4 v = *(const float4*)&part[p][mg][lane][i * 4];
                acc[i][0] += v.x; acc[i][1] += v.y; acc[i][2] += v.z; acc[i][3] += v.w;
            }
        float e[2][4], t[2];
#pragma unroll
        for (int i = 0; i < 2; ++i) {
            t[i] = 0.0f;
#pragma unroll
            for (int j = 0; j < 4; ++j) {
                e[i][j] = __builtin_amdgcn_exp2f((wsum - 2.0f * acc[i][j]) * LOG2E);
                t[i] += e[i][j];
            }
        }
#pragma unroll
        for (int o = 32; o; o >>= 1) { t[0] += __shfl_xor(t[0], o); t[1] += __shfl_xor(t[1], o); }
        float r0 = __builtin_amdgcn_rcpf(t[0]);
        float r1 = __builtin_amdgcn_rcpf(t[1]);
        int mcol = M0 + mg * 2;
#pragma unroll
        for (int j = 0; j < 4; ++j) {
            float a0 = e[0][j] * r0, a1 = e[1][j] * r1;
            *(unsigned*)&ANh[((size_t)b * DIM + n0 + j) * DIM + mcol] = hi2(a0, a1);
        }
    }
}

// ---------------- av (MFMA): 32(n)x32(d) tiles, grid 512, V hi-only (1 MFMA/step) ----------------
__global__ __launch_bounds__(256) void av_mfma(
    const ushort_t* __restrict__ ANh,
    const float* __restrict__ value, float* __restrict__ out)
{
    __shared__ __align__(16) ushort_t Ah[32 * 64], Bh[32 * 64];
    __shared__ __align__(16) float T[32][36];

    int bid = blockIdx.x;
    int b = bid & 7;
    int x = bid >> 3;
    int R0 = (x >> 3) * 32, C0 = (x & 7) * 32;
    const ushort_t* Abh = ANh + (size_t)b * DIM * DIM;
    const float*    Vb  = value + (size_t)b * DIM * DIM;

    int tid = threadIdx.x;
    int w = tid >> 6, lane = tid & 63;
    int wr = w >> 1, wc = w & 1;
    int l15 = lane & 15, l4 = lane >> 4;
    int sr = tid >> 3, skq = (tid & 7) * 8;
    int kp = tid & 31, cg = tid >> 5;

    f32x4 a0acc = {};
    uint4 ah0;
    float4 v00, v10;
    {
        size_t aa = (size_t)(R0 + sr) * DIM + skq;
        ah0 = *(const uint4*)&Abh[aa];
        const float* vp0 = &Vb[(size_t)(2 * kp)     * DIM + C0 + cg * 4];
        const float* vp1 = &Vb[(size_t)(2 * kp + 1) * DIM + C0 + cg * 4];
        v00 = *(const float4*)&vp0[0];
        v10 = *(const float4*)&vp1[0];
    }

    for (int ks = 0; ks < 4; ++ks) {
        {
            int i0 = (sr * 64 + skq) ^ ((sr & 7) << 3);
            *(uint4*)&Ah[i0] = ah0;
            float a0[4] = {v00.x, v00.y, v00.z, v00.w};
            float a1[4] = {v10.x, v10.y, v10.z, v10.w};
#pragma unroll
            for (int c = 0; c < 4; ++c) {
                int col = cg * 4 + c;
                int idx = (col * 64 + 2 * kp) ^ ((col & 7) << 3);
                *(unsigned*)&Bh[idx] = hi2(a0[c], a1[c]);
            }
        }
        __syncthreads();
        if (ks < 3) {
            int K0 = (ks + 1) * 64;
            size_t aa = (size_t)(R0 + sr) * DIM + K0 + skq;
            ah0 = *(const uint4*)&Abh[aa];
            const float* vp0 = &Vb[(size_t)(K0 + 2 * kp)     * DIM + C0 + cg * 4];
            const float* vp1 = &Vb[(size_t)(K0 + 2 * kp + 1) * DIM + C0 + cg * 4];
            v00 = *(const float4*)&vp0[0];
            v10 = *(const float4*)&vp1[0];
        }
#pragma unroll
        for (int kk = 0; kk < 2; ++kk) {
            int kb = kk * 32 + l4 * 8;
            short8 ah, bh;
            {
                int arow = wr * 16 + l15;
                int aidx = (arow * 64 + kb) ^ ((arow & 7) << 3);
                ah = *(const short8*)&Ah[aidx];
            }
            {
                int bcol = wc * 16 + l15;
                int bidx = (bcol * 64 + kb) ^ ((bcol & 7) << 3);
                bh = *(const short8*)&Bh[bidx];
            }
            a0acc = __builtin_amdgcn_mfma_f32_16x16x32_bf16(ah, bh, a0acc, 0, 0, 0);
        }
        __syncthreads();
    }

    {
        int row = wr * 16 + l4 * 4;
        int col = wc * 16 + l15;
#pragma unroll
        for (int v = 0; v < 4; ++v) T[row + v][col] = a0acc[v];
    }
    __syncthreads();
    {
        int r = tid >> 3, q = tid & 7;
        float* dst = &out[((size_t)b * DIM + R0 + r) * DIM + C0 + q * 4];
        *(float4*)&dst[0] = *(const float4*)&T[r][q * 4];
    }
}

extern "C" void kernel_launch(void* const* d_in, const int* in_sizes, int n_in,
                              void* d_out, int out_size, void* d_ws, size_t ws_size,
                              hipStream_t stream)
{
    const float* query = (const float*)d_in[0];
    const float* key   = (const float*)d_in[1];
    const float* value = (const float*)d_in[2];
    const float* Wq    = (const float*)d_in[3];
    const float* Wk    = (const float*)d_in[4];
    const float* Wv    = (const float*)d_in[5];
    float* out = (float*)d_out;

    float* EQ = (float*)d_ws;
    float* EK = EQ + N_B * DIM * DIM;
    ushort_t* ANh = (ushort_t*)(EK + N_B * DIM * DIM);

    proj_mfma            <<<512, 512, 0, stream>>>(query, key, Wq, Wk, EQ, EK);
    scores_softmax_kernel<<<512, 512, 0, stream>>>(EQ, EK, Wv, ANh);
    av_mfma              <<<512, 256, 0, stream>>>(ANh, value, out);
}

// Round 25
// 31.886 us; speedup vs baseline: 1.0372x; 1.0372x over previous
//
#include <hip/hip_runtime.h>

#define N_B 8
#define DIM 256

constexpr float C2    = 2.8853900817779268f;   // 2*log2(e)
constexpr float LOG2E = 1.4426950408889634f;

typedef __attribute__((ext_vector_type(8))) short short8;
typedef __attribute__((ext_vector_type(4))) float f32x4;
typedef unsigned short ushort_t;

__device__ __forceinline__ unsigned hi2(float a, float b) {
    return (__float_as_uint(a) >> 16) | (__float_as_uint(b) & 0xFFFF0000u);
}
__device__ __forceinline__ float trunc_res(float a) {
    return a - __uint_as_float(__float_as_uint(a) & 0xFFFF0000u);
}

// ---------------- proj (MFMA): 32x64 tiles, grid 512 (2 blocks/CU), A hi-only ----------------
__global__ __launch_bounds__(512, 2) void proj_mfma(
    const float* __restrict__ query, const float* __restrict__ key,
    const float* __restrict__ Wq, const float* __restrict__ Wk,
    float* __restrict__ EQ, float* __restrict__ EK)
{
    __shared__ __align__(16) ushort_t Ah[32 * 64], Bh[64 * 64], Bl[64 * 64];
    __shared__ __align__(16) float T[2304];

    int bid = blockIdx.x;
    int y = bid & 15;
    int x = bid >> 4;
    int b = y >> 1; bool isK = y & 1;
    const float* A    = (isK ? key : query) + b * DIM * DIM;
    const float* Wsrc = isK ? Wk : Wq;

    int R0 = (x >> 2) * 32, C0 = (x & 3) * 64;

    int tid = threadIdx.x;
    int w = tid >> 6, lane = tid & 63;
    int wr = w >> 2, wc = w & 3;
    int l15 = lane & 15, l4 = lane >> 4;

    int sr = tid >> 4, skq = (tid & 15) * 4;
    int kp = tid & 31, cg = tid >> 5;

    f32x4 acc = {};
    float4 areg;
    float4 w00, w10;

    {
        areg = *(const float4*)&A[(size_t)(R0 + sr) * DIM + skq];
        const float* wp0 = &Wsrc[(size_t)(2 * kp)     * DIM + C0 + cg * 4];
        const float* wp1 = &Wsrc[(size_t)(2 * kp + 1) * DIM + C0 + cg * 4];
        w00 = *(const float4*)&wp0[0];
        w10 = *(const float4*)&wp1[0];
    }

    for (int ks = 0; ks < 4; ++ks) {
        {
            int i0 = (sr * 64 + skq) ^ ((sr & 7) << 3);
            *(uint2*)&Ah[i0] = make_uint2(hi2(areg.x, areg.y), hi2(areg.z, areg.w));
            float a0[4] = {w00.x, w00.y, w00.z, w00.w};
            float a1[4] = {w10.x, w10.y, w10.z, w10.w};
#pragma unroll
            for (int c = 0; c < 4; ++c) {
                int col = cg * 4 + c;
                int idx = (col * 64 + 2 * kp) ^ ((col & 7) << 3);
                *(unsigned*)&Bh[idx] = hi2(a0[c], a1[c]);
                *(unsigned*)&Bl[idx] = hi2(trunc_res(a0[c]), trunc_res(a1[c]));
            }
        }
        __syncthreads();
        if (ks < 3) {
            int K0 = (ks + 1) * 64;
            areg = *(const float4*)&A[(size_t)(R0 + sr) * DIM + K0 + skq];
            const float* wp0 = &Wsrc[(size_t)(K0 + 2 * kp)     * DIM + C0 + cg * 4];
            const float* wp1 = &Wsrc[(size_t)(K0 + 2 * kp + 1) * DIM + C0 + cg * 4];
            w00 = *(const float4*)&wp0[0];
            w10 = *(const float4*)&wp1[0];
        }
#pragma unroll
        for (int kk = 0; kk < 2; ++kk) {
            int kb = kk * 32 + l4 * 8;
            short8 ah, bh, bl;
            {
                int arow = wr * 16 + l15;
                int aidx = (arow * 64 + kb) ^ ((arow & 7) << 3);
                ah = *(const short8*)&Ah[aidx];
            }
            {
                int bcol = wc * 16 + l15;
                int bidx = (bcol * 64 + kb) ^ ((bcol & 7) << 3);
                bh = *(const short8*)&Bh[bidx];
                bl = *(const short8*)&Bl[bidx];
            }
            acc = __builtin_amdgcn_mfma_f32_16x16x32_bf16(ah, bh, acc, 0, 0, 0);
            acc = __builtin_amdgcn_mfma_f32_16x16x32_bf16(ah, bl, acc, 0, 0, 0);
        }
        __syncthreads();
    }

    {
        float ev[4];
#pragma unroll
        for (int v = 0; v < 4; ++v) ev[v] = __builtin_amdgcn_exp2f(C2 * acc[v]);
        int row = wr * 16 + l4 * 4;
        int col = wc * 16 + l15;
        if (isK) {
#pragma unroll
            for (int v = 0; v < 4; ++v) T[(row + v) * 68 + col] = ev[v];
        } else {
            *(float4*)&T[col * 36 + row] = make_float4(ev[0], ev[1], ev[2], ev[3]);
        }
    }
    __syncthreads();
    if (isK) {
        int r = tid >> 4, q = tid & 15;
        float* dst = &EK[(size_t)b * DIM * DIM + (size_t)(R0 + r) * DIM + C0 + q * 4];
        *(float4*)dst = *(const float4*)&T[r * 68 + q * 4];
    } else {
        int r = tid >> 3, q = tid & 7;
        float* dst = &EQ[(size_t)b * DIM * DIM + (size_t)(C0 + r) * DIM + R0 + q * 4];
        *(float4*)dst = *(const float4*)&T[r * 36 + q * 4];
    }
}

// ---------------- fused scores + softmax(axis=n) -> attnN hi bf16 [n][m] ----------------
// 1D grid 512 (b = bid&7); MBLK=4, 512 thr = 8 waves = 4 hs x 2 mg.
// 2-way rcp combine (R23 best), 2x-unrolled chunk loop, setprio around compute.
#define SCORES_CHUNK(QC, CIDX)                                                          \
    {                                                                                   \
        float4 wv4 = *(const float4*)&Ws[(CIDX) * 16 + hs * 4];                         \
        float wva[4] = {wv4.x, wv4.y, wv4.z, wv4.w};                                    \
        float eka[2][4];                                                                \
        _Pragma("unroll")                                                               \
        for (int i = 0; i < 2; ++i) {                                                   \
            float4 e4 = *(const float4*)&Eks[mg * 2 + i][(CIDX) * 16 + hs * 4];         \
            eka[i][0] = e4.x; eka[i][1] = e4.y; eka[i][2] = e4.z; eka[i][3] = e4.w;     \
        }                                                                               \
        __builtin_amdgcn_s_setprio(1);                                                  \
        _Pragma("unroll")                                                               \
        for (int hh = 0; hh < 2; ++hh) {                                                \
            float q0a[4] = {QC[hh * 2].x, QC[hh * 2].y, QC[hh * 2].z, QC[hh * 2].w};    \
            float q1a[4] = {QC[hh * 2 + 1].x, QC[hh * 2 + 1].y,                         \
                            QC[hh * 2 + 1].z, QC[hh * 2 + 1].w};                        \
            float w0 = wva[hh * 2], w1 = wva[hh * 2 + 1];                               \
            _Pragma("unroll")                                                           \
            for (int i = 0; i < 2; ++i) {                                               \
                float e0 = eka[i][hh * 2], e1 = eka[i][hh * 2 + 1];                     \
                _Pragma("unroll")                                                       \
                for (int j = 0; j < 4; ++j) {                                           \
                    float d0 = fmaf(q0a[j], e0, 1.0f);                                  \
                    float d1 = fmaf(q1a[j], e1, 1.0f);                                  \
                    float num = fmaf(w0, d1, w1 * d0);                                  \
                    acc[i][j] = fmaf(num, __builtin_amdgcn_rcpf(d0 * d1), acc[i][j]);   \
                }                                                                       \
            }                                                                           \
        }                                                                               \
        __builtin_amdgcn_s_setprio(0);                                                  \
    }

__global__ __launch_bounds__(512, 2) void scores_softmax_kernel(
    const float* __restrict__ EQ, const float* __restrict__ EK,
    const float* __restrict__ Wv, ushort_t* __restrict__ ANh)
{
    int bid = blockIdx.x;
    int b  = bid & 7;
    int M0 = (bid >> 3) * 4;
    const float* Qb = EQ + b * DIM * DIM;   // [h][n]
    const float* Kb = EK + b * DIM * DIM;   // [m][h]

    __shared__ __align__(16) float Eks[4][DIM];
    __shared__ __align__(16) float Ws[DIM];
    __shared__ __align__(16) float part[3][2][64][8];

    int tid  = threadIdx.x;
    int w = tid >> 6, lane = tid & 63;
    int hs = w & 3, mg = w >> 2;
    int n0 = lane * 4;

    {
        int row = tid >> 7, h2 = (tid & 127) * 2;
        *(float2*)&Eks[row][h2] = *(const float2*)&Kb[(M0 + row) * DIM + h2];
    }
    if (tid < 64) *(float4*)&Ws[tid * 4] = *(const float4*)&Wv[tid * 4];

    float wsum = Wv[lane] + Wv[lane + 64] + Wv[lane + 128] + Wv[lane + 192];
#pragma unroll
    for (int o = 32; o; o >>= 1) wsum += __shfl_xor(wsum, o);
    __syncthreads();

    float acc[2][4] = {};
    const float* qbase = Qb + (hs * 4) * 256 + n0;

    float4 qA[4], qB[4];
#pragma unroll
    for (int r = 0; r < 4; ++r) qA[r] = *(const float4*)&qbase[r * 256];

    for (int c = 0; c < 16; c += 2) {
        {
            const float* qc = qbase + (c + 1) * 4096;
#pragma unroll
            for (int r = 0; r < 4; ++r) qB[r] = *(const float4*)&qc[r * 256];
        }
        SCORES_CHUNK(qA, c)
        if (c + 2 < 16) {
            const float* qc = qbase + (c + 2) * 4096;
#pragma unroll
            for (int r = 0; r < 4; ++r) qA[r] = *(const float4*)&qc[r * 256];
        }
        SCORES_CHUNK(qB, (c + 1))
    }

    if (hs) {
#pragma unroll
        for (int i = 0; i < 2; ++i) {
            float4 v = make_float4(acc[i][0], acc[i][1], acc[i][2], acc[i][3]);
            *(float4*)&part[hs - 1][mg][lane][i * 4] = v;
        }
    }
    __syncthreads();
    if (hs == 0) {
#pragma unroll
        for (int p = 0; p < 3; ++p)
#pragma unroll
            for (int i = 0; i < 2; ++i) {
                float4 v = *(const float4*)&part[p][mg][lane][i * 4];
                acc[i][0] += v.x; acc[i][1] += v.y; acc[i][2] += v.z; acc[i][3] += v.w;
            }
        float e[2][4], t[2];
#pragma unroll
        for (int i = 0; i < 2; ++i) {
            t[i] = 0.0f;
#pragma unroll
            for (int j = 0; j < 4; ++j) {
                e[i][j] = __builtin_amdgcn_exp2f((wsum - 2.0f * acc[i][j]) * LOG2E);
                t[i] += e[i][j];
            }
        }
#pragma unroll
        for (int o = 32; o; o >>= 1) { t[0] += __shfl_xor(t[0], o); t[1] += __shfl_xor(t[1], o); }
        float r0 = __builtin_amdgcn_rcpf(t[0]);
        float r1 = __builtin_amdgcn_rcpf(t[1]);
        int mcol = M0 + mg * 2;
#pragma unroll
        for (int j = 0; j < 4; ++j) {
            float a0 = e[0][j] * r0, a1 = e[1][j] * r1;
            *(unsigned*)&ANh[((size_t)b * DIM + n0 + j) * DIM + mcol] = hi2(a0, a1);
        }
    }
}

// ---------------- av (MFMA): 32(n)x32(d) tiles, grid 512, V hi-only (1 MFMA/step) ----------------
__global__ __launch_bounds__(256) void av_mfma(
    const ushort_t* __restrict__ ANh,
    const float* __restrict__ value, float* __restrict__ out)
{
    __shared__ __align__(16) ushort_t Ah[32 * 64], Bh[32 * 64];
    __shared__ __align__(16) float T[32][36];

    int bid = blockIdx.x;
    int b = bid & 7;
    int x = bid >> 3;
    int R0 = (x >> 3) * 32, C0 = (x & 7) * 32;
    const ushort_t* Abh = ANh + (size_t)b * DIM * DIM;
    const float*    Vb  = value + (size_t)b * DIM * DIM;

    int tid = threadIdx.x;
    int w = tid >> 6, lane = tid & 63;
    int wr = w >> 1, wc = w & 1;
    int l15 = lane & 15, l4 = lane >> 4;
    int sr = tid >> 3, skq = (tid & 7) * 8;
    int kp = tid & 31, cg = tid >> 5;

    f32x4 a0acc = {};
    uint4 ah0;
    float4 v00, v10;
    {
        size_t aa = (size_t)(R0 + sr) * DIM + skq;
        ah0 = *(const uint4*)&Abh[aa];
        const float* vp0 = &Vb[(size_t)(2 * kp)     * DIM + C0 + cg * 4];
        const float* vp1 = &Vb[(size_t)(2 * kp + 1) * DIM + C0 + cg * 4];
        v00 = *(const float4*)&vp0[0];
        v10 = *(const float4*)&vp1[0];
    }

    for (int ks = 0; ks < 4; ++ks) {
        {
            int i0 = (sr * 64 + skq) ^ ((sr & 7) << 3);
            *(uint4*)&Ah[i0] = ah0;
            float a0[4] = {v00.x, v00.y, v00.z, v00.w};
            float a1[4] = {v10.x, v10.y, v10.z, v10.w};
#pragma unroll
            for (int c = 0; c < 4; ++c) {
                int col = cg * 4 + c;
                int idx = (col * 64 + 2 * kp) ^ ((col & 7) << 3);
                *(unsigned*)&Bh[idx] = hi2(a0[c], a1[c]);
            }
        }
        __syncthreads();
        if (ks < 3) {
            int K0 = (ks + 1) * 64;
            size_t aa = (size_t)(R0 + sr) * DIM + K0 + skq;
            ah0 = *(const uint4*)&Abh[aa];
            const float* vp0 = &Vb[(size_t)(K0 + 2 * kp)     * DIM + C0 + cg * 4];
            const float* vp1 = &Vb[(size_t)(K0 + 2 * kp + 1) * DIM + C0 + cg * 4];
            v00 = *(const float4*)&vp0[0];
            v10 = *(const float4*)&vp1[0];
        }
#pragma unroll
        for (int kk = 0; kk < 2; ++kk) {
            int kb = kk * 32 + l4 * 8;
            short8 ah, bh;
            {
                int arow = wr * 16 + l15;
                int aidx = (arow * 64 + kb) ^ ((arow & 7) << 3);
                ah = *(const short8*)&Ah[aidx];
            }
            {
                int bcol = wc * 16 + l15;
                int bidx = (bcol * 64 + kb) ^ ((bcol & 7) << 3);
                bh = *(const short8*)&Bh[bidx];
            }
            a0acc = __builtin_amdgcn_mfma_f32_16x16x32_bf16(ah, bh, a0acc, 0, 0, 0);
        }
        __syncthreads();
    }

    {
        int row = wr * 16 + l4 * 4;
        int col = wc * 16 + l15;
#pragma unroll
        for (int v = 0; v < 4; ++v) T[row + v][col] = a0acc[v];
    }
    __syncthreads();
    {
        int r = tid >> 3, q = tid & 7;
        float* dst = &out[((size_t)b * DIM + R0 + r) * DIM + C0 + q * 4];
        *(float4*)&dst[0] = *(const float4*)&T[r][q * 4];
    }
}

extern "C" void kernel_launch(void* const* d_in, const int* in_sizes, int n_in,
                              void* d_out, int out_size, void* d_ws, size_t ws_size,
                              hipStream_t stream)
{
    const float* query = (const float*)d_in[0];
    const float* key   = (const float*)d_in[1];
    const float* value = (const float*)d_in[2];
    const float* Wq    = (const float*)d_in[3];
    const float* Wk    = (const float*)d_in[4];
    const float* Wv    = (const float*)d_in[5];
    float* out = (float*)d_out;

    float* EQ = (float*)d_ws;
    float* EK = EQ + N_B * DIM * DIM;
    ushort_t* ANh = (ushort_t*)(EK + N_B * DIM * DIM);

    proj_mfma            <<<512, 512, 0, stream>>>(query, key, Wq, Wk, EQ, EK);
    scores_softmax_kernel<<<512, 512, 0, stream>>>(EQ, EK, Wv, ANh);
    av_mfma              <<<512, 256, 0, stream>>>(ANh, value, out);
}